// Round 1
// baseline (131.384 us; speedup 1.0000x reference)
//
#include <hip/hip_runtime.h>

#define BATCH   262144
#define FIN     128      // fan_in
#define FINP    129      // fan_in + 1 (bias col)
#define FOUT    128
#define TB      256      // threads per block
#define ROWS_PER_TILE 128
#define TR      8        // rows per thread
#define TC      8        // cols per thread
// 16 col-groups x 16 row-groups = 256 threads; 16*8=128 cols, 16*8=128 rows.

__global__ __launch_bounds__(TB, 2)
void hashed_fwd(const float* __restrict__ a, const float* __restrict__ W,
                const int* __restrict__ hidx, float* __restrict__ out,
                int row_tiles) {
    // WT[j][i] = W[hash_idx[i][j]]  — transposed so a thread's 8 cols are contiguous.
    __shared__ float WT[FINP][FOUT];   // 129*128*4 = 66048 B -> 2 blocks/CU

    for (int f = threadIdx.x; f < FOUT * FINP; f += TB) {
        int i = f / FINP;          // fan_out index
        int j = f - i * FINP;      // 0..128
        WT[j][i] = W[hidx[f]];
    }
    __syncthreads();

    const int cg = threadIdx.x & 15;   // column group
    const int rg = threadIdx.x >> 4;   // row group
    const int c0 = cg * TC;

    for (int tile = blockIdx.x; tile < row_tiles; tile += gridDim.x) {
        const int r0 = tile * ROWS_PER_TILE + rg * TR;

        // init accumulators with the bias column (a_ext[128] == 1)
        float acc[TR][TC];
        #pragma unroll
        for (int c = 0; c < TC; ++c) {
            float b = WT[FIN][c0 + c];
            #pragma unroll
            for (int r = 0; r < TR; ++r) acc[r][c] = b;
        }

        const float* arow = a + (size_t)r0 * FIN;

        #pragma unroll 4
        for (int j = 0; j < FIN; j += 4) {
            float4 av[TR];
            #pragma unroll
            for (int r = 0; r < TR; ++r)
                av[r] = *reinterpret_cast<const float4*>(arow + (size_t)r * FIN + j);

            #pragma unroll
            for (int jj = 0; jj < 4; ++jj) {
                float4 w0 = *reinterpret_cast<const float4*>(&WT[j + jj][c0]);
                float4 w1 = *reinterpret_cast<const float4*>(&WT[j + jj][c0 + 4]);
                float wv[TC] = {w0.x, w0.y, w0.z, w0.w, w1.x, w1.y, w1.z, w1.w};
                #pragma unroll
                for (int r = 0; r < TR; ++r) {
                    float aj = (jj == 0) ? av[r].x : (jj == 1) ? av[r].y
                             : (jj == 2) ? av[r].z : av[r].w;
                    #pragma unroll
                    for (int c = 0; c < TC; ++c)
                        acc[r][c] = fmaf(aj, wv[c], acc[r][c]);
                }
            }
        }

        #pragma unroll
        for (int r = 0; r < TR; ++r) {
            float* orow = out + (size_t)(r0 + r) * FOUT + c0;
            *reinterpret_cast<float4*>(orow)     = make_float4(acc[r][0], acc[r][1], acc[r][2], acc[r][3]);
            *reinterpret_cast<float4*>(orow + 4) = make_float4(acc[r][4], acc[r][5], acc[r][6], acc[r][7]);
        }
    }
}

extern "C" void kernel_launch(void* const* d_in, const int* in_sizes, int n_in,
                              void* d_out, int out_size, void* d_ws, size_t ws_size,
                              hipStream_t stream) {
    const float* a    = (const float*)d_in[0];
    const float* W    = (const float*)d_in[1];
    const int*   hidx = (const int*)d_in[2];
    float*       out  = (float*)d_out;

    const int row_tiles = BATCH / ROWS_PER_TILE;   // 2048
    hipLaunchKernelGGL(hashed_fwd, dim3(512), dim3(TB), 0, stream,
                       a, W, hidx, out, row_tiles);
}